// Round 1
// baseline (365.497 us; speedup 1.0000x reference)
//
#include <hip/hip_runtime.h>

// Workspace layout (floats). Requires ws_size >= ~118 MB.
#define H1_OFF   0u            // h1: 4096*16*16*16 = 16777216 floats
#define H2_OFF   16777216u     // h2: 4096*32*8*8   =  8388608 floats
#define H3_OFF   25165824u     // h3: 4096*64*4*4   =  4194304 floats
#define W2T_OFF  29360128u     // w2 transposed [ic][ky][kx][oc] : 16*9*32  = 4608
#define W3T_OFF  29364736u     // w3 transposed [ic][ky][kx][oc] : 32*9*64  = 18432
// total = 29383168 floats = 117.53 MB

// ---------------------------------------------------------------- transpose
__global__ __launch_bounds__(256) void transpose_weights(
    const float* __restrict__ w2, const float* __restrict__ w3,
    float* __restrict__ ws) {
  int i = blockIdx.x * 256 + threadIdx.x;
  if (i < 4608) {                       // w2 [32][16*9] -> w2t [16*9][32]
    int oc = i / 144, r = i % 144;
    ws[W2T_OFF + r * 32 + oc] = w2[i];
  }
  int j = i - 4608;
  if (j >= 0 && j < 18432) {            // w3 [64][32*9] -> w3t [32*9][64]
    int oc = j / 288, r = j % 288;
    ws[W3T_OFF + r * 64 + oc] = w3[j];
  }
}

// ------------------------------------------------------------------- conv1
// x[4096,3,32,32] -> relu+pool -> h1[4096,16,16,16]. 1 image per block.
__global__ __launch_bounds__(256) void conv1_kernel(
    const float* __restrict__ x, const float* __restrict__ w1,
    const float* __restrict__ b1, float* __restrict__ h1) {
  __shared__ __align__(16) float s_in[3 * 34 * 34];  // padded, 13.9 KB
  __shared__ __align__(16) float s_w[27 * 16];       // [ic*9+t][oc]
  const int tid = threadIdx.x;
  const int b = blockIdx.x;

  for (int i = tid; i < 3 * 34 * 34; i += 256) s_in[i] = 0.f;
  __syncthreads();
  for (int i = tid; i < 3 * 1024; i += 256) {
    int c = i >> 10, rem = i & 1023, y = rem >> 5, xx = rem & 31;
    s_in[c * 1156 + (y + 1) * 34 + (xx + 1)] = x[b * 3072 + i];
  }
  for (int i = tid; i < 432; i += 256) {
    int oc = i / 27, r = i % 27;
    s_w[r * 16 + oc] = w1[i];
  }
  __syncthreads();

  const int ocg = tid & 3;        // 4 groups x 4 oc = 16 oc
  const int tile = tid >> 2;      // 64 tiles (8x8 of 4x4-conv regions)
  const int ty = tile >> 3, tx = tile & 7;
  const int Y = 4 * ty, X = 4 * tx;

  float acc[4][16];
  #pragma unroll
  for (int i = 0; i < 4; ++i)
    #pragma unroll
    for (int j = 0; j < 16; ++j) acc[i][j] = 0.f;

  #pragma unroll
  for (int ic = 0; ic < 3; ++ic) {
    float win[6][6];
    const int base = ic * 1156 + Y * 34 + X;
    #pragma unroll
    for (int r = 0; r < 6; ++r)
      #pragma unroll
      for (int c = 0; c < 6; ++c) win[r][c] = s_in[base + r * 34 + c];
    #pragma unroll
    for (int ky = 0; ky < 3; ++ky)
      #pragma unroll
      for (int kx = 0; kx < 3; ++kx) {
        const float4 w = *(const float4*)&s_w[(ic * 9 + ky * 3 + kx) * 16 + ocg * 4];
        #pragma unroll
        for (int r = 0; r < 4; ++r)
          #pragma unroll
          for (int c = 0; c < 4; ++c) {
            const float v = win[r + ky][c + kx];
            acc[0][r * 4 + c] = fmaf(v, w.x, acc[0][r * 4 + c]);
            acc[1][r * 4 + c] = fmaf(v, w.y, acc[1][r * 4 + c]);
            acc[2][r * 4 + c] = fmaf(v, w.z, acc[2][r * 4 + c]);
            acc[3][r * 4 + c] = fmaf(v, w.w, acc[3][r * 4 + c]);
          }
      }
  }
  #pragma unroll
  for (int oci = 0; oci < 4; ++oci) {
    const int oc = ocg * 4 + oci;
    const float bias = b1[oc];
    #pragma unroll
    for (int pyi = 0; pyi < 2; ++pyi)
      #pragma unroll
      for (int pxi = 0; pxi < 2; ++pxi) {
        const int r0 = 2 * pyi, c0 = 2 * pxi;
        float m = fmaxf(fmaxf(acc[oci][r0 * 4 + c0], acc[oci][r0 * 4 + c0 + 1]),
                        fmaxf(acc[oci][(r0 + 1) * 4 + c0], acc[oci][(r0 + 1) * 4 + c0 + 1]));
        const int py = 2 * ty + pyi, px = 2 * tx + pxi;
        h1[((b * 16 + oc) << 8) + py * 16 + px] = fmaxf(m + bias, 0.f);
      }
  }
}

// ------------------------------------------------------------------- conv2
// h1[4096,16,16,16] -> relu+pool -> h2[4096,32,8,8]. 2 images per block.
__global__ __launch_bounds__(256) void conv2_kernel(
    const float* __restrict__ h1, const float* __restrict__ w2t,
    const float* __restrict__ b2, float* __restrict__ h2) {
  __shared__ __align__(16) float s_in[2 * 16 * 18 * 18];  // 41.5 KB
  const int tid = threadIdx.x;
  const int b0 = blockIdx.x * 2;

  for (int i = tid; i < 10368; i += 256) s_in[i] = 0.f;
  __syncthreads();
  for (int i = tid; i < 8192; i += 256) {
    int img = i >> 12, rem = i & 4095;
    int c = rem >> 8, y = (rem >> 4) & 15, xx = rem & 15;
    s_in[img * 5184 + c * 324 + (y + 1) * 18 + (xx + 1)] = h1[(b0 + img) * 4096 + rem];
  }
  __syncthreads();

  const int ocg = tid & 7;            // 8 groups x 4 oc = 32
  const int tile = (tid >> 3) & 15;   // 16 tiles
  const int img = tid >> 7;           // 2 images
  const int ty = tile >> 2, tx = tile & 3;
  const int Y = 4 * ty, X = 4 * tx;
  const float* __restrict__ wbase = w2t + ocg * 4;

  float acc[4][16];
  #pragma unroll
  for (int i = 0; i < 4; ++i)
    #pragma unroll
    for (int j = 0; j < 16; ++j) acc[i][j] = 0.f;

  const int ibase0 = img * 5184 + Y * 18 + X;
  for (int ic = 0; ic < 16; ++ic) {
    float win[6][6];
    const int base = ibase0 + ic * 324;
    #pragma unroll
    for (int r = 0; r < 6; ++r)
      #pragma unroll
      for (int c = 0; c < 6; ++c) win[r][c] = s_in[base + r * 18 + c];
    #pragma unroll
    for (int t = 0; t < 9; ++t) {
      const float4 w = *(const float4*)&wbase[(ic * 9 + t) * 32];
      const int ky = t / 3, kx = t % 3;
      #pragma unroll
      for (int r = 0; r < 4; ++r)
        #pragma unroll
        for (int c = 0; c < 4; ++c) {
          const float v = win[r + ky][c + kx];
          acc[0][r * 4 + c] = fmaf(v, w.x, acc[0][r * 4 + c]);
          acc[1][r * 4 + c] = fmaf(v, w.y, acc[1][r * 4 + c]);
          acc[2][r * 4 + c] = fmaf(v, w.z, acc[2][r * 4 + c]);
          acc[3][r * 4 + c] = fmaf(v, w.w, acc[3][r * 4 + c]);
        }
    }
  }
  #pragma unroll
  for (int oci = 0; oci < 4; ++oci) {
    const int oc = ocg * 4 + oci;
    const float bias = b2[oc];
    #pragma unroll
    for (int pyi = 0; pyi < 2; ++pyi)
      #pragma unroll
      for (int pxi = 0; pxi < 2; ++pxi) {
        const int r0 = 2 * pyi, c0 = 2 * pxi;
        float m = fmaxf(fmaxf(acc[oci][r0 * 4 + c0], acc[oci][r0 * 4 + c0 + 1]),
                        fmaxf(acc[oci][(r0 + 1) * 4 + c0], acc[oci][(r0 + 1) * 4 + c0 + 1]));
        const int py = 2 * ty + pyi, px = 2 * tx + pxi;
        h2[((b0 + img) * 32 + oc) * 64 + py * 8 + px] = fmaxf(m + bias, 0.f);
      }
  }
}

// ------------------------------------------------------------------- conv3
// h2[4096,32,8,8] -> relu+pool -> h3[4096,64,4,4]. 4 images per block.
__global__ __launch_bounds__(256) void conv3_kernel(
    const float* __restrict__ h2, const float* __restrict__ w3t,
    const float* __restrict__ b3, float* __restrict__ h3) {
  __shared__ __align__(16) float s_in[4 * 32 * 10 * 10];  // 51.2 KB
  const int tid = threadIdx.x;
  const int b0 = blockIdx.x * 4;

  for (int i = tid; i < 12800; i += 256) s_in[i] = 0.f;
  __syncthreads();
  for (int i = tid; i < 8192; i += 256) {
    int img = i >> 11, rem = i & 2047;
    int c = rem >> 6, y = (rem >> 3) & 7, xx = rem & 7;
    s_in[img * 3200 + c * 100 + (y + 1) * 10 + (xx + 1)] = h2[(b0 + img) * 2048 + rem];
  }
  __syncthreads();

  const int ocg = tid & 15;           // 16 groups x 4 oc = 64
  const int tile = (tid >> 4) & 3;    // 4 tiles
  const int img = tid >> 6;           // 4 images (one wave per image)
  const int ty = tile >> 1, tx = tile & 1;
  const int Y = 4 * ty, X = 4 * tx;
  const float* __restrict__ wbase = w3t + ocg * 4;

  float acc[4][16];
  #pragma unroll
  for (int i = 0; i < 4; ++i)
    #pragma unroll
    for (int j = 0; j < 16; ++j) acc[i][j] = 0.f;

  const int ibase0 = img * 3200 + Y * 10 + X;
  for (int ic = 0; ic < 32; ++ic) {
    float win[6][6];
    const int base = ibase0 + ic * 100;
    #pragma unroll
    for (int r = 0; r < 6; ++r)
      #pragma unroll
      for (int c = 0; c < 6; ++c) win[r][c] = s_in[base + r * 10 + c];
    #pragma unroll
    for (int t = 0; t < 9; ++t) {
      const float4 w = *(const float4*)&wbase[(ic * 9 + t) * 64];
      const int ky = t / 3, kx = t % 3;
      #pragma unroll
      for (int r = 0; r < 4; ++r)
        #pragma unroll
        for (int c = 0; c < 4; ++c) {
          const float v = win[r + ky][c + kx];
          acc[0][r * 4 + c] = fmaf(v, w.x, acc[0][r * 4 + c]);
          acc[1][r * 4 + c] = fmaf(v, w.y, acc[1][r * 4 + c]);
          acc[2][r * 4 + c] = fmaf(v, w.z, acc[2][r * 4 + c]);
          acc[3][r * 4 + c] = fmaf(v, w.w, acc[3][r * 4 + c]);
        }
    }
  }
  #pragma unroll
  for (int oci = 0; oci < 4; ++oci) {
    const int oc = ocg * 4 + oci;
    const float bias = b3[oc];
    #pragma unroll
    for (int pyi = 0; pyi < 2; ++pyi)
      #pragma unroll
      for (int pxi = 0; pxi < 2; ++pxi) {
        const int r0 = 2 * pyi, c0 = 2 * pxi;
        float m = fmaxf(fmaxf(acc[oci][r0 * 4 + c0], acc[oci][r0 * 4 + c0 + 1]),
                        fmaxf(acc[oci][(r0 + 1) * 4 + c0], acc[oci][(r0 + 1) * 4 + c0 + 1]));
        const int py = 2 * ty + pyi, px = 2 * tx + pxi;
        h3[((b0 + img) * 64 + oc) * 16 + py * 4 + px] = fmaxf(m + bias, 0.f);
      }
  }
}

// ---------------------------------------------------------------------- fc
// h3[4096,1024] @ fc_w[10,1024]^T + fc_b -> out[4096,10]. One wave per image.
__global__ __launch_bounds__(256) void fc_kernel(
    const float* __restrict__ h3, const float* __restrict__ fw,
    const float* __restrict__ fb, float* __restrict__ out) {
  const int tid = threadIdx.x;
  const int lane = tid & 63;
  const int b = blockIdx.x * 4 + (tid >> 6);
  float hv[16];
  #pragma unroll
  for (int i = 0; i < 16; ++i) hv[i] = h3[b * 1024 + i * 64 + lane];
  #pragma unroll
  for (int j = 0; j < 10; ++j) {
    float dot = 0.f;
    #pragma unroll
    for (int i = 0; i < 16; ++i)
      dot = fmaf(hv[i], fw[j * 1024 + i * 64 + lane], dot);
    #pragma unroll
    for (int s = 32; s > 0; s >>= 1) dot += __shfl_xor(dot, s, 64);
    if (lane == 0) out[b * 10 + j] = dot + fb[j];
  }
}

// -------------------------------------------------------------------- launch
extern "C" void kernel_launch(void* const* d_in, const int* in_sizes, int n_in,
                              void* d_out, int out_size, void* d_ws, size_t ws_size,
                              hipStream_t stream) {
  const float* x   = (const float*)d_in[0];
  const float* w1  = (const float*)d_in[1];
  const float* b1  = (const float*)d_in[2];
  const float* w2  = (const float*)d_in[3];
  const float* b2  = (const float*)d_in[4];
  const float* w3  = (const float*)d_in[5];
  const float* b3  = (const float*)d_in[6];
  const float* fcw = (const float*)d_in[7];
  const float* fcb = (const float*)d_in[8];
  float* ws  = (float*)d_ws;
  float* out = (float*)d_out;

  hipLaunchKernelGGL(transpose_weights, dim3(90), dim3(256), 0, stream, w2, w3, ws);
  hipLaunchKernelGGL(conv1_kernel, dim3(4096), dim3(256), 0, stream,
                     x, w1, b1, ws + H1_OFF);
  hipLaunchKernelGGL(conv2_kernel, dim3(2048), dim3(256), 0, stream,
                     ws + H1_OFF, ws + W2T_OFF, b2, ws + H2_OFF);
  hipLaunchKernelGGL(conv3_kernel, dim3(1024), dim3(256), 0, stream,
                     ws + H2_OFF, ws + W3T_OFF, b3, ws + H3_OFF);
  hipLaunchKernelGGL(fc_kernel, dim3(1024), dim3(256), 0, stream,
                     ws + H3_OFF, fcw, fcb, out);
}